// Round 1
// baseline (79.502 us; speedup 1.0000x reference)
//
#include <hip/hip_runtime.h>

// Quantum circuit sim — radix-16, layer 0 folded into a product-state init
// (R12, verified absmax=0), and layer-1 RZs factored OUT of the gate
// math: per-pass, the four RZ·RY gates == (4 real RY gates) x (one 4-wire
// diagonal with 16 slot-constant values e^{i*0.5*sum(+-z)}), since per-wire
// diagonals commute with RYs on other wires. The DPP wires (12,13) phase
// collapses to ONE per-thread constant e_t (amp bits 1,0 are thread-fixed).
// All gates (both layers) are real RY matrices staged as a single
// float4 {ca,-sa,sa,ca} — half the gate-constant LDS reads + rfl's of R12.
//
// Structure (R11/R12, verified): 3 hexa passes/layer x 2 entangling layers,
// packed-fp32 v2f math, CNOT chain folded into store-address XORs with the
// prefix-xor perm D(o), wires 12,13 via quad_perm DPP inside p=2 (extended
// store delta through bits 1,0), final layer RZ-free by |.|^2 invariance,
// measurement + linear head fused in registers. 6 sweeps, 5 barriers.
//
// LDS swizzle slot = i ^ ((i>>4)&15) ^ ((i>>8)&15) ^ ((i>>9)&16), GF2-linear.
// Constants into SGPRs via readfirstlane; no indexable per-thread arrays
// (R2-R6 big-body regime spilled pathologically; FETCH_SIZE = spill canary).
//
// R13 — DIAGNOSTIC ROUND (intentional, remove next round):
// The qsim kernel (~38.9 us inferred) sits just BELOW the harness's 256 MB
// poison-fill dispatches (39.16-39.40 us), so rocprof top-5 shows only the
// fills and we have NO counters for the kernel itself. A single
// s_sleep(63) (~4032 clk ~= 1.7 us) is added before the reduction to push
// the kernel into the top-5 and expose VALUBusy / LDS_BANK_CONFLICT /
// FETCH_SIZE / VGPR_Count with known ~4% dilution. Math untouched.

#define NW      14
#define NSTATE  (1 << NW)
#define TPB     1024
#define NLAYERS 3

typedef float v2f __attribute__((ext_vector_type(2)));

__device__ __forceinline__ int swz(int i) {
    return i ^ ((i >> 4) & 15) ^ ((i >> 8) & 15) ^ ((i >> 9) & 16);
}
__device__ __forceinline__ v2f vswp(v2f a) { return __builtin_shufflevector(a, a, 1, 0); }
__device__ __forceinline__ v2f vspl(float x) { v2f r; r.x = x;  r.y = x; return r; }
__device__ __forceinline__ v2f vpm(float x)  { v2f r; r.x = -x; r.y = x; return r; }
__device__ __forceinline__ float rfl(float x) {
    return __int_as_float(__builtin_amdgcn_readfirstlane(__float_as_int(x)));
}
// complex multiply (a.x+i a.y)(b.x+i b.y)
__device__ __forceinline__ v2f cml(v2f a, v2f b) {
    return vspl(a.x) * b + vpm(a.y) * vswp(b);
}
template <int CTRL>
__device__ __forceinline__ v2f dpp2(v2f a) {
    v2f r;
    r.x = __int_as_float(__builtin_amdgcn_update_dpp(
              0, __float_as_int(a.x), CTRL, 0xF, 0xF, true));
    r.y = __int_as_float(__builtin_amdgcn_update_dpp(
              0, __float_as_int(a.y), CTRL, 0xF, 0xF, true));
    return r;
}
// real 2x2 gate on (a,d)
__device__ __forceinline__ void pgr(v2f& a, v2f& d,
                                    float x00, float x01, float x10, float x11) {
    const v2f na = vspl(x00) * a + vspl(x01) * d;
    const v2f nd = vspl(x10) * a + vspl(x11) * d;
    a = na; d = nd;
}

// real gate constants {ca,-sa,sa,ca} -> SGPRs
#define GATE_R(pre, g) \
    const float4 pre##V = gtr[g]; \
    const float pre##0 = rfl(pre##V.x), pre##1 = rfl(pre##V.y), \
                pre##2 = rfl(pre##V.z), pre##3 = rfl(pre##V.w);
#define PGR4(a, d, pre) pgr(a, d, pre##0, pre##1, pre##2, pre##3)

// 4-wire diagonal: one float4 = phases for slots (2k, 2k+1)
#define PH2(aE, aO, k) { \
    const float4 Z_ = zph4[zb + (k)]; \
    const float ex_ = rfl(Z_.x), ey_ = rfl(Z_.y); \
    const float ox_ = rfl(Z_.z), oy_ = rfl(Z_.w); \
    aE = vspl(ex_)*aE + vpm(ey_)*vswp(aE); \
    aO = vspl(ox_)*aO + vpm(oy_)*vswp(aO); }

// real DPP lane gate
#define LGR1(aX, CT) { const v2f p_ = dpp2<CT>(aX); \
    aX = vspl(cor)*aX + vspl(cpr)*p_; }
#define LGR_ALL(CT) \
    LGR1(a0,CT) LGR1(a1,CT) LGR1(a2,CT) LGR1(a3,CT) \
    LGR1(a4,CT) LGR1(a5,CT) LGR1(a6,CT) LGR1(a7,CT) \
    LGR1(a8,CT) LGR1(a9,CT) LGR1(aA,CT) LGR1(aB,CT) \
    LGR1(aC,CT) LGR1(aD,CT) LGR1(aE,CT) LGR1(aF,CT)

// per-thread wires-12/13 phase
#define ETA(aX) { aX = vspl(et.x)*aX + vpm(et.y)*vswp(aX); }
#define ETA_ALL \
    ETA(a0) ETA(a1) ETA(a2) ETA(a3) ETA(a4) ETA(a5) ETA(a6) ETA(a7) \
    ETA(a8) ETA(a9) ETA(aA) ETA(aB) ETA(aC) ETA(aD) ETA(aE) ETA(aF)

// measurement: Dn = dest nibble (cs=0), par = parity(o)
#define MEAS(aX, Dn, par) { \
    const float m_ = ((Dn)&8?-h8:h8)+((Dn)&4?-h9:h9)+((Dn)&2?-h10:h10)+((Dn)&1?-h11:h11); \
    const float cf_ = coefHigh + sc*m_ + ((par)? -Wp : Wp); \
    acc += (aX.x*aX.x + aX.y*aX.y)*cf_; }

__global__ void __launch_bounds__(TPB)
qsim_kernel(const float* __restrict__ state_batch,   // [B, NW]
            const float* __restrict__ var_params,    // [NLAYERS, NW, 3]
            const float* __restrict__ head_w,        // [NW]
            const float* __restrict__ head_b,        // [1]
            float* __restrict__ out)                 // [B]
{
    __shared__ v2f    psi[NSTATE];          // 128 KiB
    __shared__ float4 gtr[2 * NW];          // real RY gates, layers 1,2
    __shared__ float4 zph4[3 * 8];          // L1 per-pass 4-wire diag (16 slots)
    __shared__ v2f    zph12[4];             // L1 wires 12,13 diag by t&3
    __shared__ v2f    vws[NW][2];           // layer-0 product columns
    __shared__ float  hws[NW];
    __shared__ float  red[TPB / 64];

    const int t    = threadIdx.x;
    const int lane = t & 63;
    const int wave = t >> 6;
    const int b    = blockIdx.x;

    // ---- staging ----
    if (t < NW) {
        float sx, cx, sy, cy, sz, cz;
        sincosf(0.5f * state_batch[b * NW + t], &sx, &cx);
        sincosf(0.5f * var_params[t * 3 + 0], &sy, &cy);        // L0 RY
        sincosf(0.5f * var_params[t * 3 + 1], &sz, &cz);        // L0 RZ
        const float tr = cy * cx, ti = sy * sx;
        const float br = sy * cx, bi = -cy * sx;
        v2f v0, v1;
        v0.x = cz * tr + sz * ti;  v0.y = cz * ti - sz * tr;
        v1.x = cz * br - sz * bi;  v1.y = cz * bi + sz * br;
        vws[t][0] = v0; vws[t][1] = v1;
    }
    if (t >= 64 && t < 64 + 2 * NW) {       // real RY gates for layers 1,2
        const int g = t - 64;               // g = (l-1)*NW + w
        float sa, ca;
        sincosf(0.5f * var_params[(NW + g) * 3 + 0], &sa, &ca);
        gtr[g] = make_float4(ca, -sa, sa, ca);
    }
    if (t >= 128 && t < 128 + NW) hws[t - 128] = head_w[t - 128];
    if (t >= 192 && t < 240) {              // L1 per-pass 4-wire diagonals
        const int k = t - 192, p = k >> 4, o = k & 15;
        float ang = 0.f;
#pragma unroll
        for (int j = 0; j < 4; ++j) {       // o bit (3-j) <-> wire 4p+j
            const float z = var_params[(NW + 4 * p + j) * 3 + 1];
            ang += ((o >> (3 - j)) & 1) ? 0.5f * z : -0.5f * z;
        }
        float s_, c_; sincosf(ang, &s_, &c_);
        if (o & 1) { zph4[p * 8 + (o >> 1)].z = c_; zph4[p * 8 + (o >> 1)].w = s_; }
        else       { zph4[p * 8 + (o >> 1)].x = c_; zph4[p * 8 + (o >> 1)].y = s_; }
    }
    if (t >= 240 && t < 244) {              // L1 wires 12,13 diag by t&3
        const int k2 = t - 240;
        const float z12 = var_params[(NW + 12) * 3 + 1];
        const float z13 = var_params[(NW + 13) * 3 + 1];
        const float ang = ((k2 & 2) ? 0.5f * z12 : -0.5f * z12)
                        + ((k2 & 1) ? 0.5f * z13 : -0.5f * z13);
        float s_, c_; sincosf(ang, &s_, &c_);
        v2f e; e.x = c_; e.y = s_;
        zph12[k2] = e;
    }
    __syncthreads();

    float acc = 0.f;

#pragma unroll 1
    for (int l = 1; l < NLAYERS; ++l) {
        const int gl = (l - 1) * NW;
#pragma unroll 1
        for (int p = 0; p < 3; ++p) {
            const int SB = 10 - 4 * p;
            const int LO = 1 << SB;
            const int S0 = swz(LO), S1 = swz(LO << 1);
            const int S2 = swz(LO << 2), S3 = swz(LO << 3);
            const int M  = S3 ^ S2 ^ S1 ^ S0;
            const int zb = p * 8;
            GATE_R(ga, gl + 4 * p);     GATE_R(gb, gl + 4 * p + 1);
            GATE_R(gc, gl + 4 * p + 2); GATE_R(gd, gl + 4 * p + 3);

            const int i0 = ((t >> SB) << (SB + 4)) | (t & (LO - 1));
            const int s  = swz(i0);

            v2f a0, a1, a2, a3, a4, a5, a6, a7;
            v2f a8, a9, aA, aB, aC, aD, aE, aF;
            if (l == 1 && p == 0) {
                // ---- post-layer-0 product state, chain perm folded ----
                v2f base = cml(vws[5][((t >> 8) ^ (t >> 9)) & 1],
                               vws[6][((t >> 7) ^ (t >> 8)) & 1]);
                v2f m2   = cml(vws[7][((t >> 6) ^ (t >> 7)) & 1],
                               vws[8][((t >> 5) ^ (t >> 6)) & 1]);
                v2f m3   = cml(vws[9][((t >> 4) ^ (t >> 5)) & 1],
                               vws[10][((t >> 3) ^ (t >> 4)) & 1]);
                v2f m4   = cml(vws[11][((t >> 2) ^ (t >> 3)) & 1],
                               vws[12][((t >> 1) ^ (t >> 2)) & 1]);
                base = cml(base, m2);
                m3   = cml(m3, m4);
                base = cml(base, m3);
                base = cml(base, vws[13][(t ^ (t >> 1)) & 1]);
                const int t9 = (t >> 9) & 1;
                const v2f B0 = cml(base, vws[4][t9]);
                const v2f B1 = cml(base, vws[4][t9 ^ 1]);
                const v2f w3B00 = cml(vws[3][0], B0);
                const v2f w3B01 = cml(vws[3][1], B1);
                const v2f w3B10 = cml(vws[3][1], B0);
                const v2f w3B11 = cml(vws[3][0], B1);
                v2f p_, t20, t21;
                p_ = cml(vws[0][0], vws[1][0]);
                t20 = cml(p_, vws[2][0]); t21 = cml(p_, vws[2][1]);
                a0 = cml(t20, w3B00); a1 = cml(t20, w3B01);
                a2 = cml(t21, w3B10); a3 = cml(t21, w3B11);
                p_ = cml(vws[0][0], vws[1][1]);
                t20 = cml(p_, vws[2][1]); t21 = cml(p_, vws[2][0]);
                a4 = cml(t20, w3B00); a5 = cml(t20, w3B01);
                a6 = cml(t21, w3B10); a7 = cml(t21, w3B11);
                p_ = cml(vws[0][1], vws[1][1]);
                t20 = cml(p_, vws[2][0]); t21 = cml(p_, vws[2][1]);
                a8 = cml(t20, w3B00); a9 = cml(t20, w3B01);
                aA = cml(t21, w3B10); aB = cml(t21, w3B11);
                p_ = cml(vws[0][1], vws[1][0]);
                t20 = cml(p_, vws[2][1]); t21 = cml(p_, vws[2][0]);
                aC = cml(t20, w3B00); aD = cml(t20, w3B01);
                aE = cml(t21, w3B10); aF = cml(t21, w3B11);
            } else {
                a0 = psi[s];                a1 = psi[s ^ S0];
                a2 = psi[s ^ S1];           a3 = psi[s ^ S1 ^ S0];
                a4 = psi[s ^ S2];           a5 = psi[s ^ S2 ^ S0];
                a6 = psi[s ^ S2 ^ S1];      a7 = psi[s ^ S2 ^ S1 ^ S0];
                a8 = psi[s ^ S3];           a9 = psi[s ^ S3 ^ S0];
                aA = psi[s ^ S3 ^ S1];      aB = psi[s ^ S3 ^ S1 ^ S0];
                aC = psi[s ^ S3 ^ S2];      aD = psi[s ^ S3 ^ S2 ^ S0];
                aE = psi[s ^ S3 ^ S2 ^ S1]; aF = psi[s ^ M];
            }

            // 4 real RY gates (bits b3..b0)
            PGR4(a0, a8, ga); PGR4(a1, a9, ga); PGR4(a2, aA, ga); PGR4(a3, aB, ga);
            PGR4(a4, aC, ga); PGR4(a5, aD, ga); PGR4(a6, aE, ga); PGR4(a7, aF, ga);
            PGR4(a0, a4, gb); PGR4(a1, a5, gb); PGR4(a2, a6, gb); PGR4(a3, a7, gb);
            PGR4(a8, aC, gb); PGR4(a9, aD, gb); PGR4(aA, aE, gb); PGR4(aB, aF, gb);
            PGR4(a0, a2, gc); PGR4(a1, a3, gc); PGR4(a4, a6, gc); PGR4(a5, a7, gc);
            PGR4(a8, aA, gc); PGR4(a9, aB, gc); PGR4(aC, aE, gc); PGR4(aD, aF, gc);
            PGR4(a0, a1, gd); PGR4(a2, a3, gd); PGR4(a4, a5, gd); PGR4(a6, a7, gd);
            PGR4(a8, a9, gd); PGR4(aA, aB, gd); PGR4(aC, aD, gd); PGR4(aE, aF, gd);

            if (l == 1) {
                // 4-wire RZ diagonal (slot constants)
                PH2(a0, a1, 0) PH2(a2, a3, 1) PH2(a4, a5, 2) PH2(a6, a7, 3)
                PH2(a8, a9, 4) PH2(aA, aB, 5) PH2(aC, aD, 6) PH2(aE, aF, 7)
            }

            if (p < 2) {
                const bool cs = ((t >> SB) & 1) != 0;
                const int e = s ^ (cs ? M : 0);
                psi[e]                = a0; psi[e ^ S0]           = a1;
                psi[e ^ S1 ^ S0]      = a2; psi[e ^ S1]           = a3;
                psi[e ^ S2 ^ S1 ^ S0] = a4; psi[e ^ S2 ^ S1]      = a5;
                psi[e ^ S2]           = a6; psi[e ^ S2 ^ S0]      = a7;
                psi[e ^ M]            = a8; psi[e ^ S3 ^ S2 ^ S1] = a9;
                psi[e ^ S3 ^ S2]      = aA; psi[e ^ S3 ^ S2 ^ S0] = aB;
                psi[e ^ S3]           = aC; psi[e ^ S3 ^ S0]      = aD;
                psi[e ^ S3 ^ S1 ^ S0] = aE; psi[e ^ S3 ^ S1]      = aF;
                __syncthreads();
            } else if (l < NLAYERS - 1) {
                // real lane gates wires 12 (0x4E), 13 (0xB1) + e_t phase
                GATE_R(gu, gl + 12);
                GATE_R(gv, gl + 13);
                {
                    const float cor = gu0;
                    const float cpr = (t & 2) ? gu2 : gu1;
                    LGR_ALL(0x4E)
                }
                {
                    const float cor = gv0;
                    const float cpr = (t & 1) ? gv2 : gv1;
                    LGR_ALL(0xB1)
                }
                { const v2f et = zph12[t & 3]; ETA_ALL }
                // extended store: chain through bits 1,0
                const bool cs = ((t >> SB) & 1) != 0;
                const int e = s ^ (cs ? (M ^ 3) : 0) ^ ((t >> 1) & 1);
                psi[e]                    = a0; psi[e ^ S0 ^ 3]           = a1;
                psi[e ^ S1 ^ S0 ^ 3]      = a2; psi[e ^ S1]               = a3;
                psi[e ^ S2 ^ S1 ^ S0 ^ 3] = a4; psi[e ^ S2 ^ S1]          = a5;
                psi[e ^ S2]               = a6; psi[e ^ S2 ^ S0 ^ 3]      = a7;
                psi[e ^ M ^ 3]            = a8; psi[e ^ S3 ^ S2 ^ S1]     = a9;
                psi[e ^ S3 ^ S2]          = aA; psi[e ^ S3 ^ S2 ^ S0 ^ 3] = aB;
                psi[e ^ S3]               = aC; psi[e ^ S3 ^ S0 ^ 3]      = aD;
                psi[e ^ S3 ^ S1 ^ S0 ^ 3] = aE; psi[e ^ S3 ^ S1]          = aF;
                __syncthreads();
            } else {
                // final layer p=2: real lane gates + fused measurement
                GATE_R(gu, gl + 12);
                GATE_R(gv, gl + 13);
                {
                    const float cor = gu0;
                    const float cpr = (t & 2) ? gu2 : gu1;
                    LGR_ALL(0x4E)
                }
                {
                    const float cor = gv0;
                    const float cpr = (t & 1) ? gv2 : gv1;
                    LGR_ALL(0xB1)
                }
                const float h8 = hws[8], h9 = hws[9], h10 = hws[10], h11 = hws[11];
                const float h12 = hws[12], h13 = hws[13];
                float coefHigh = 0.f;           // wires 0..7 from t bits 9..2
#pragma unroll
                for (int j = 0; j < 8; ++j)
                    coefHigh += ((t >> (9 - j)) & 1) ? -hws[j] : hws[j];
                const bool cs = ((t >> SB) & 1) != 0;
                const float sc = cs ? -1.f : 1.f;
                const float w12_0 = (t & 2) ? -h12 : h12;
                const float w13_0 = (((t >> 1) ^ t) & 1) ? -h13 : h13;
                const float Ssum = w12_0 + w13_0;
                const float Wp = cs ? -Ssum : Ssum;
                MEAS(a0, 0, 0)  MEAS(a1, 1, 1)  MEAS(a2, 3, 1)  MEAS(a3, 2, 0)
                MEAS(a4, 7, 1)  MEAS(a5, 6, 0)  MEAS(a6, 4, 0)  MEAS(a7, 5, 1)
                MEAS(a8, 15, 1) MEAS(a9, 14, 0) MEAS(aA, 12, 0) MEAS(aB, 13, 1)
                MEAS(aC, 8, 0)  MEAS(aD, 9, 1)  MEAS(aE, 11, 1) MEAS(aF, 10, 0)
            }
        }
    }

    // R13 diagnostic slug: ~4032 clocks of idle per wave, pushes this kernel
    // above the harness's 39.2-39.4 us poison fills in the rocprof top-5 so
    // we finally see its counters. Remove next round.
    __builtin_amdgcn_s_sleep(63);

    // ---- block reduction + head ----
#pragma unroll
    for (int off = 32; off > 0; off >>= 1)
        acc += __shfl_down(acc, off, 64);
    if (lane == 0) red[wave] = acc;
    __syncthreads();
    if (t == 0) {
        float s = 0.f;
#pragma unroll
        for (int i = 0; i < TPB / 64; ++i) s += red[i];
        out[b] = s + head_b[0];
    }
}

extern "C" void kernel_launch(void* const* d_in, const int* in_sizes, int n_in,
                              void* d_out, int out_size, void* d_ws, size_t ws_size,
                              hipStream_t stream) {
    const float* state_batch = (const float*)d_in[0];
    const float* var_params  = (const float*)d_in[1];
    const float* head_w      = (const float*)d_in[2];
    const float* head_b      = (const float*)d_in[3];
    float* out = (float*)d_out;
    qsim_kernel<<<dim3(out_size), dim3(TPB), 0, stream>>>(
        state_batch, var_params, head_w, head_b, out);
}